// Round 5
// baseline (529.410 us; speedup 1.0000x reference)
//
#include <hip/hip_runtime.h>
#include <stdint.h>

typedef unsigned short u16;
typedef unsigned int   u32;
typedef __attribute__((ext_vector_type(2))) float f32x2;
typedef __attribute__((ext_vector_type(4))) float f32x4;
typedef __attribute__((ext_vector_type(8))) short s16x8;

typedef const __attribute__((address_space(1))) void as1_void;
typedef __attribute__((address_space(3))) void as3_void;

__device__ __forceinline__ u16 f2bf(float f) {
    u32 x = __float_as_uint(f);
    x += 0x7fffu + ((x >> 16) & 1u);
    return (u16)(x >> 16);
}
__device__ __forceinline__ float tanh_fast(float x) {
    return 1.f - 2.f / (__expf(2.f * x) + 1.f);
}
__device__ __forceinline__ float sigm(float x) {
    return 1.f / (1.f + __expf(-x));
}
// pack 8 f32 (two f32x4) -> 8 bf16 by truncation (v_perm byte-selects)
__device__ __forceinline__ s16x8 pack8(f32x4 x0, f32x4 x1) {
    union { s16x8 v; u32 w[4]; } r;
    r.w[0] = __builtin_amdgcn_perm(__float_as_uint(x0[1]), __float_as_uint(x0[0]), 0x07060302u);
    r.w[1] = __builtin_amdgcn_perm(__float_as_uint(x0[3]), __float_as_uint(x0[2]), 0x07060302u);
    r.w[2] = __builtin_amdgcn_perm(__float_as_uint(x1[1]), __float_as_uint(x1[0]), 0x07060302u);
    r.w[3] = __builtin_amdgcn_perm(__float_as_uint(x1[3]), __float_as_uint(x1[2]), 0x07060302u);
    return r.v;
}

#define BM 128
#define BN 128

// C[r,n] = sum_k A[r,k]*B[n,k]; fp32 operands, K-contiguous.
// Staging: global_load_lds dwordx4 direct HBM->LDS, raw fp32 tiles, BK=32,
// double-buffered (64 KB). LDS dest linear (HW: wave base + lane*16);
// swizzle achieved by XOR-permuting the per-lane GLOBAL source chunk
// (chunk' = chunk ^ (row&7)); fragment reads apply the same XOR -> bank-clean.
// bf16 conversion at fragment-read time (2x ds_read_b128 + 4 v_perm).
// EPI 1: s += tanh(acc + hidb[(r/196)*N+n] + bias1[n]+bias2[n]) * wscore[n];
//        16-lane reduce -> atomicAdd(scores[r])
// EPI 2: atomicAdd(outF[r*N+n], acc)   (split-K accumulate)
template<int EPI>
__global__ __launch_bounds__(256) void gemm32(
    const float* __restrict__ Ag, const float* __restrict__ B1, const float* __restrict__ B2,
    int lda, int ldb1, int ldb2, int ksplitB, int N, int klen,
    float* __restrict__ outF,
    const float* __restrict__ bias1, const float* __restrict__ bias2,
    const float* __restrict__ hidb, const float* __restrict__ wscore,
    float* __restrict__ scores)
{
    __shared__ __align__(16) float As[2][BM * 32];
    __shared__ __align__(16) float Bs[2][BN * 32];
    const int tid = threadIdx.x;
    const int l   = tid & 63;
    const int w   = tid >> 6;

    // XCD-aware bijective remap: consecutive logical blocks (sharing an
    // A-panel) land on one XCD -> A/B panels L2-resident.
    const int nbx = gridDim.x;
    const int nwg = nbx * gridDim.y;
    const int p   = blockIdx.x + blockIdx.y * nbx;
    const int per = nwg >> 3;
    const int lg  = (p & 7) * per + (p >> 3);
    const int n0  = (lg % nbx) * BN;
    const int m0  = (lg / nbx) * BM;

    const int kbeg   = blockIdx.z * klen;
    const int nsteps = klen >> 5;
    const int wr = (w >> 1) * 64;
    const int wc = (w & 1) * 64;

    // Stage one 128x32 f32 tile pair into As[buf]/Bs[buf].
    // slot = c*256 + tid; row = slot>>3; chunk16B = slot&7; src chunk ^= row&7.
    auto STAGE = [&](int buf, int kt) {
        #pragma unroll
        for (int c = 0; c < 4; ++c) {
            const int slot = c * 256 + tid;
            const int row  = slot >> 3;
            const int sch  = (slot & 7) ^ (row & 7);
            const int wbase = (c * 256 + w * 64) * 4;   // wave-uniform float idx
            const float* ga = Ag + (size_t)(m0 + row) * lda + kt + sch * 4;
            __builtin_amdgcn_global_load_lds((as1_void*)ga, (as3_void*)&As[buf][wbase], 16, 0, 0);
            const int kg = kt + sch * 4;
            const float* gb = (kg < ksplitB)
                ? (B1 + (size_t)(n0 + row) * ldb1 + kg)
                : (B2 + (size_t)(n0 + row) * ldb2 + (kg - ksplitB));
            __builtin_amdgcn_global_load_lds((as1_void*)gb, (as3_void*)&Bs[buf][wbase], 16, 0, 0);
        }
    };

    f32x4 acc[4][4] = {};
    STAGE(0, kbeg);
    __syncthreads();   // drains vmcnt -> buf0 ready

    int cur = 0;
    for (int s = 0; s < nsteps; ++s) {
        if (s + 1 < nsteps) STAGE(cur ^ 1, kbeg + (s + 1) * 32);  // prefetch next
        // fragments: lane reads k = (l>>4)*8 .. +7 (chunks 2*(l>>4), +1, XOR-swizzled)
        s16x8 af[4], bg[4];
        const int cb = (l >> 4) * 2;
        #pragma unroll
        for (int i = 0; i < 4; ++i) {
            const int row = wr + i * 16 + (l & 15);
            f32x4 x0 = *(const f32x4*)&As[cur][row * 32 + (cb ^ (row & 7)) * 4];
            f32x4 x1 = *(const f32x4*)&As[cur][row * 32 + ((cb + 1) ^ (row & 7)) * 4];
            af[i] = pack8(x0, x1);
        }
        #pragma unroll
        for (int j = 0; j < 4; ++j) {
            const int row = wc + j * 16 + (l & 15);
            f32x4 x0 = *(const f32x4*)&Bs[cur][row * 32 + (cb ^ (row & 7)) * 4];
            f32x4 x1 = *(const f32x4*)&Bs[cur][row * 32 + ((cb + 1) ^ (row & 7)) * 4];
            bg[j] = pack8(x0, x1);
        }
        #pragma unroll
        for (int i = 0; i < 4; ++i)
            #pragma unroll
            for (int j = 0; j < 4; ++j)
                acc[i][j] = __builtin_amdgcn_mfma_f32_16x16x32_bf16(af[i], bg[j], acc[i][j], 0, 0, 0);
        __syncthreads();   // drain prefetch vmcnt + protect cur from overwrite
        cur ^= 1;
    }

    // C/D layout (m89-verified): col = lane&15, row = (lane>>4)*4 + reg
    const int col0 = l & 15;
    const int rgrp = l >> 4;

    if (EPI == 1) {
        float wsv[4], bs[4]; int gcol[4];
        #pragma unroll
        for (int j = 0; j < 4; ++j) {
            gcol[j] = n0 + wc + j * 16 + col0;
            wsv[j] = wscore[gcol[j]];
            bs[j]  = bias1[gcol[j]] + bias2[gcol[j]];
        }
        #pragma unroll
        for (int i = 0; i < 4; ++i) {
            #pragma unroll
            for (int q = 0; q < 4; ++q) {
                int grow = m0 + wr + i * 16 + rgrp * 4 + q;
                int bb = grow / 196;
                const float* hb = hidb + (size_t)bb * N;
                float s = 0.f;
                #pragma unroll
                for (int j = 0; j < 4; ++j) {
                    float x = acc[i][j][q] + hb[gcol[j]] + bs[j];
                    s += tanh_fast(x) * wsv[j];
                }
                s += __shfl_xor(s, 1);
                s += __shfl_xor(s, 2);
                s += __shfl_xor(s, 4);
                s += __shfl_xor(s, 8);
                if (col0 == 0) atomicAdd(&scores[grow], s);
            }
        }
    } else {
        #pragma unroll
        for (int j = 0; j < 4; ++j) {
            int gcol = n0 + wc + j * 16 + col0;
            #pragma unroll
            for (int i = 0; i < 4; ++i)
                #pragma unroll
                for (int q = 0; q < 4; ++q) {
                    int grow = m0 + wr + i * 16 + rgrp * 4 + q;
                    atomicAdd(&outF[(size_t)grow * N + gcol], acc[i][j][q]);
                }
        }
    }
}

// One block per batch row b: softmax over L=196 scores; att_res = sum_l p_l*att[b,l,:]
// (f32x4 loads, block halves cover even/odd l, LDS cross-half reduce);
// X[b] = [xt | att_res | h_prev] fp32 (K=1536) for the gates GEMM.
__global__ __launch_bounds__(256) void softmax_attres(
    const float* __restrict__ att, const float* __restrict__ scores,
    const float* __restrict__ xt, const float* __restrict__ h0,
    float* __restrict__ X)
{
    const int b = blockIdx.x;
    const int tid = threadIdx.x;
    __shared__ float p[200];
    __shared__ float redm[4], reds[4];
    __shared__ float accu[128 * 4];

    float s = (tid < 196) ? scores[b * 196 + tid] : -3.0e38f;
    float m = s;
    #pragma unroll
    for (int d = 32; d; d >>= 1) m = fmaxf(m, __shfl_xor(m, d));
    if ((tid & 63) == 0) redm[tid >> 6] = m;
    __syncthreads();
    m = fmaxf(fmaxf(redm[0], redm[1]), fmaxf(redm[2], redm[3]));

    float e = (tid < 196) ? __expf(s - m) : 0.f;
    float sum = e;
    #pragma unroll
    for (int d = 32; d; d >>= 1) sum += __shfl_xor(sum, d);
    if ((tid & 63) == 0) reds[tid >> 6] = sum;
    __syncthreads();
    sum = reds[0] + reds[1] + reds[2] + reds[3];
    if (tid < 196) p[tid] = e / sum;
    __syncthreads();

    const float* attb = att + (size_t)b * 196 * 512;
    const int half = tid >> 7;           // waves 0,1 -> even l; waves 2,3 -> odd l
    const int e4   = (tid & 127) * 4;    // feature base 0..508
    f32x4 a = {0.f, 0.f, 0.f, 0.f};
    for (int lq = half; lq < 196; lq += 2) {
        f32x4 u = *(const f32x4*)(attb + (size_t)lq * 512 + e4);
        float pl = p[lq];
        a[0] = fmaf(pl, u[0], a[0]);
        a[1] = fmaf(pl, u[1], a[1]);
        a[2] = fmaf(pl, u[2], a[2]);
        a[3] = fmaf(pl, u[3], a[3]);
    }
    if (half) *(f32x4*)(accu + (tid & 127) * 4) = a;
    __syncthreads();

    float* Xr = X + (size_t)b * 1536;
    if (!half) {
        f32x4 o = *(const f32x4*)(accu + tid * 4);
        a[0] += o[0]; a[1] += o[1]; a[2] += o[2]; a[3] += o[3];
        *(f32x4*)(Xr + 512 + e4) = a;
    }
    f32x2 xv = ((const f32x2*)(xt + (size_t)b * 512))[tid];
    ((f32x2*)Xr)[tid] = xv;
    f32x2 hv = ((const f32x2*)(h0 + (size_t)b * 512))[tid];
    ((f32x2*)(Xr + 1024))[tid] = hv;
}

// Elementwise LSTM: gate order i,f,g,o. out = [h | h | c] fp32.
__global__ __launch_bounds__(256) void lstm_ep(
    const float* __restrict__ gates, const float* __restrict__ c0, float* __restrict__ out)
{
    int idx = blockIdx.x * 256 + threadIdx.x;     // 0..262143
    int b = idx >> 9, hh = idx & 511;
    const float* g = gates + ((size_t)b << 11);
    float i_ = sigm(g[hh]);
    float f_ = sigm(g[512 + hh]);
    float g_ = tanh_fast(g[1024 + hh]);
    float o_ = sigm(g[1536 + hh]);
    float c = f_ * c0[idx] + i_ * g_;
    float h = o_ * tanh_fast(c);
    out[idx] = h;
    out[262144 + idx] = h;
    out[524288 + idx] = c;
}

extern "C" void kernel_launch(void* const* d_in, const int* in_sizes, int n_in,
                              void* d_out, int out_size, void* d_ws, size_t ws_size,
                              hipStream_t stream) {
    const float* xt   = (const float*)d_in[0];
    // d_in[1] = fc_feats (unused by reference)
    const float* att  = (const float*)d_in[2];
    const float* h0   = (const float*)d_in[3];
    const float* c0   = (const float*)d_in[4];
    const float* Wctx = (const float*)d_in[5];
    const float* bctx = (const float*)d_in[6];
    const float* Whid = (const float*)d_in[7];
    const float* bhid = (const float*)d_in[8];
    const float* wsc  = (const float*)d_in[9];
    // d_in[10] = b_score (cancels under softmax)
    const float* Wih  = (const float*)d_in[11];
    const float* Whh  = (const float*)d_in[12];
    float* out = (float*)d_out;

    char* ws = (char*)d_ws;
    float* hidb   = (float*)(ws);                 // 512*512 f32   = 1,048,576 B
    float* scores = (float*)(ws + 1048576);       // 100352 f32    =   401,408 B
    float* gates  = (float*)(ws + 1449984);       // 512*2048 f32  = 4,194,304 B
    float* X      = (float*)(ws + 5644288);       // 512*1536 f32  = 3,145,728 B

    // zero the atomically-accumulated regions (hidb + scores + gates)
    hipMemsetAsync(ws, 0, 5644288, stream);

    // 1) hidb[b,a] += h_prev @ W_hid^T      (split-K=4; biases folded into EPI1)
    gemm32<2><<<dim3(4, 4, 4), 256, 0, stream>>>(
        h0, Whid, Whid, 512, 512, 512, 1 << 28, 512, 128,
        hidb, nullptr, nullptr, nullptr, nullptr, nullptr);

    // 2) scores[b,l] += sum_a tanh(att@Wctx^T + hidb + b_hid + b_ctx)*w_score
    gemm32<1><<<dim3(4, 784, 1), 256, 0, stream>>>(
        att, Wctx, Wctx, 512, 512, 512, 1 << 28, 512, 512,
        nullptr, bhid, bctx, hidb, wsc, scores);

    // 3) softmax + att_res + X = [xt | att_res | h_prev] (fp32)
    softmax_attres<<<512, 256, 0, stream>>>(att, scores, xt, h0, X);

    // 4) gates = X @ [W_ih | W_hh]^T   (M=512,N=2048,K=1536, split-K=4)
    gemm32<2><<<dim3(16, 4, 4), 256, 0, stream>>>(
        X, Wih, Whh, 1536, 1024, 512, 1024, 2048, 384,
        gates, nullptr, nullptr, nullptr, nullptr, nullptr);

    // 5) elementwise LSTM -> out = [h | h | c] fp32
    lstm_ep<<<1024, 256, 0, stream>>>(gates, c0, out);
}

// Round 13
// 498.579 us; speedup vs baseline: 1.0618x; 1.0618x over previous
//
#include <hip/hip_runtime.h>
#include <stdint.h>

typedef unsigned short u16;
typedef unsigned int   u32;
typedef __attribute__((ext_vector_type(2))) float f32x2;
typedef __attribute__((ext_vector_type(4))) float f32x4;
typedef __attribute__((ext_vector_type(8))) short s16x8;

typedef const __attribute__((address_space(1))) void as1_void;
typedef __attribute__((address_space(3))) void as3_void;

__device__ __forceinline__ u16 f2bf(float f) {
    u32 x = __float_as_uint(f);
    x += 0x7fffu + ((x >> 16) & 1u);
    return (u16)(x >> 16);
}
__device__ __forceinline__ float tanh_fast(float x) {
    return 1.f - 2.f / (__expf(2.f * x) + 1.f);
}
__device__ __forceinline__ float sigm(float x) {
    return 1.f / (1.f + __expf(-x));
}
// pack 8 f32 (two f32x4) -> 8 bf16 by truncation (v_perm byte-selects)
__device__ __forceinline__ s16x8 pack8(f32x4 x0, f32x4 x1) {
    union { s16x8 v; u32 w[4]; } r;
    r.w[0] = __builtin_amdgcn_perm(__float_as_uint(x0[1]), __float_as_uint(x0[0]), 0x07060302u);
    r.w[1] = __builtin_amdgcn_perm(__float_as_uint(x0[3]), __float_as_uint(x0[2]), 0x07060302u);
    r.w[2] = __builtin_amdgcn_perm(__float_as_uint(x1[1]), __float_as_uint(x1[0]), 0x07060302u);
    r.w[3] = __builtin_amdgcn_perm(__float_as_uint(x1[3]), __float_as_uint(x1[2]), 0x07060302u);
    return r.v;
}

#define BM 128
#define BN 128
#define BK 64

// C[r,n] = sum_k A[r,k]*B[n,k]; B is bf16 (pre-converted), A is f32 (AF32) or bf16.
// m97-faithful: 128x128 tile, BK=64, global_load_lds dwordx4 (contiguous source,
// linear LDS dest), single-buffered 2-barrier K-loop, 48KB LDS -> 3 blocks/CU.
// A f32 tiles packed to bf16 at fragment-read time (2x ds_read_b128 + 4 v_perm).
// EPI 1: s += tanh(acc + hidb[(r/196)*N+n] + bias1[n]+bias2[n]) * wscore[n];
//        16-lane reduce -> atomicAdd(scores[r])
// EPI 2: atomicAdd(outF[r*N+n], acc)   (split-K accumulate)
template<int EPI, bool AF32>
__global__ __launch_bounds__(256) void gemm(
    const void* __restrict__ Ag, const u16* __restrict__ Bg,
    int lda, int ldb, int N, int klen,
    float* __restrict__ outF,
    const float* __restrict__ bias1, const float* __restrict__ bias2,
    const float* __restrict__ hidb, const float* __restrict__ wscore,
    float* __restrict__ scores)
{
    constexpr int ABYTES = AF32 ? (BM * BK * 4) : (BM * BK * 2);
    __shared__ __align__(16) char Abuf[ABYTES];
    __shared__ __align__(16) u16 Bsb[BN * BK];
    const int tid = threadIdx.x;
    const int l   = tid & 63;
    const int w   = tid >> 6;

    // XCD-aware bijective remap (nwg % 8 == 0 for all our grids)
    const int nbx = gridDim.x;
    const int nwg = nbx * gridDim.y;
    const int p   = blockIdx.x + blockIdx.y * nbx;
    const int per = nwg >> 3;
    const int lg  = (p & 7) * per + (p >> 3);
    const int n0  = (lg % nbx) * BN;
    const int m0  = (lg / nbx) * BM;

    const int kbeg   = blockIdx.z * klen;
    const int nsteps = klen / BK;
    const int wr = (w >> 1) * 64;
    const int wc = (w & 1) * 64;

    auto STAGE = [&](int kt) {
        if constexpr (AF32) {
            #pragma unroll
            for (int c = 0; c < 8; ++c) {            // 32 KB: 8 x 4KB rounds
                const int slot = c * 256 + tid;
                const int row = slot >> 4, ch = slot & 15;   // 16 x 16B chunks/row
                const float* ga = (const float*)Ag + (size_t)(m0 + row) * lda + kt + ch * 4;
                __builtin_amdgcn_global_load_lds((as1_void*)ga,
                    (as3_void*)(Abuf + (c * 256 + w * 64) * 16), 16, 0, 0);
            }
        } else {
            #pragma unroll
            for (int c = 0; c < 4; ++c) {            // 16 KB: 4 x 4KB rounds
                const int slot = c * 256 + tid;
                const int row = slot >> 3, ch = slot & 7;    // 8 x 16B chunks/row
                const u16* ga = (const u16*)Ag + (size_t)(m0 + row) * lda + kt + ch * 8;
                __builtin_amdgcn_global_load_lds((as1_void*)ga,
                    (as3_void*)(Abuf + (c * 256 + w * 64) * 16), 16, 0, 0);
            }
        }
        #pragma unroll
        for (int c = 0; c < 4; ++c) {                // B: 16 KB
            const int slot = c * 256 + tid;
            const int row = slot >> 3, ch = slot & 7;
            const u16* gb = Bg + (size_t)(n0 + row) * ldb + kt + ch * 8;
            __builtin_amdgcn_global_load_lds((as1_void*)gb,
                (as3_void*)((char*)Bsb + (c * 256 + w * 64) * 16), 16, 0, 0);
        }
    };

    f32x4 acc[4][4] = {};
    const int k0 = (l >> 4) * 8;

    for (int s = 0; s < nsteps; ++s) {
        STAGE(kbeg + s * BK);
        __syncthreads();     // compiler emits vmcnt(0) drain; tile visible
        #pragma unroll
        for (int kk = 0; kk < BK; kk += 32) {
            s16x8 af[4], bg[4];
            #pragma unroll
            for (int i = 0; i < 4; ++i) {
                const int row = wr + i * 16 + (l & 15);
                if constexpr (AF32) {
                    const float* ap = (const float*)Abuf + row * BK + kk + k0;
                    af[i] = pack8(*(const f32x4*)ap, *(const f32x4*)(ap + 4));
                } else {
                    af[i] = *(const s16x8*)((const u16*)Abuf + row * BK + kk + k0);
                }
            }
            #pragma unroll
            for (int j = 0; j < 4; ++j) {
                const int row = wc + j * 16 + (l & 15);
                bg[j] = *(const s16x8*)(Bsb + row * BK + kk + k0);
            }
            #pragma unroll
            for (int i = 0; i < 4; ++i)
                #pragma unroll
                for (int j = 0; j < 4; ++j)
                    acc[i][j] = __builtin_amdgcn_mfma_f32_16x16x32_bf16(af[i], bg[j], acc[i][j], 0, 0, 0);
        }
        __syncthreads();     // all reads done before next overwrite
    }

    // C/D layout (m89-verified): col = lane&15, row = (lane>>4)*4 + reg
    const int col0 = l & 15;
    const int rgrp = l >> 4;

    if (EPI == 1) {
        float wsv[4], bs[4]; int gcol[4];
        #pragma unroll
        for (int j = 0; j < 4; ++j) {
            gcol[j] = n0 + wc + j * 16 + col0;
            wsv[j] = wscore[gcol[j]];
            bs[j]  = bias1[gcol[j]] + bias2[gcol[j]];
        }
        #pragma unroll
        for (int i = 0; i < 4; ++i) {
            #pragma unroll
            for (int q = 0; q < 4; ++q) {
                int grow = m0 + wr + i * 16 + rgrp * 4 + q;
                int bb = grow / 196;
                const float* hb = hidb + (size_t)bb * N;
                float s = 0.f;
                #pragma unroll
                for (int j = 0; j < 4; ++j) {
                    float x = acc[i][j][q] + hb[gcol[j]] + bs[j];
                    s += tanh_fast(x) * wsv[j];
                }
                s += __shfl_xor(s, 1);
                s += __shfl_xor(s, 2);
                s += __shfl_xor(s, 4);
                s += __shfl_xor(s, 8);
                if (col0 == 0) atomicAdd(&scores[grow], s);
            }
        }
    } else {
        #pragma unroll
        for (int j = 0; j < 4; ++j) {
            int gcol = n0 + wc + j * 16 + col0;
            #pragma unroll
            for (int i = 0; i < 4; ++i)
                #pragma unroll
                for (int q = 0; q < 4; ++q) {
                    int grow = m0 + wr + i * 16 + rgrp * 4 + q;
                    atomicAdd(&outF[(size_t)grow * N + gcol], acc[i][j][q]);
                }
        }
    }
}

// Convert weights f32 -> bf16 (truncation), incl. [W_ih | W_hh] k-concat into Wg.
// gid layout: [0,32768) Wctx; [32768,65536) Whid; [65536,458752) Wg (2048x1536).
__global__ __launch_bounds__(256) void cvt_w(
    const float* __restrict__ Wctx, const float* __restrict__ Whid,
    const float* __restrict__ Wih,  const float* __restrict__ Whh,
    u16* __restrict__ Wctxb, u16* __restrict__ Whidb, u16* __restrict__ Wgb)
{
    const int gid = blockIdx.x * 256 + threadIdx.x;   // 458752 total groups of 8
    const float* src;
    u16* dst;
    if (gid < 32768) {
        src = Wctx + (size_t)gid * 8;
        dst = Wctxb + (size_t)gid * 8;
    } else if (gid < 65536) {
        src = Whid + (size_t)(gid - 32768) * 8;
        dst = Whidb + (size_t)(gid - 32768) * 8;
    } else {
        const int g2 = gid - 65536;          // 0..393215
        const int n  = g2 / 192;             // 192 groups of 8 per 1536-row
        const int k8 = (g2 - n * 192) * 8;   // 0..1528
        dst = Wgb + (size_t)n * 1536 + k8;
        src = (k8 < 1024) ? (Wih + (size_t)n * 1024 + k8)
                          : (Whh + (size_t)n * 512 + (k8 - 1024));
    }
    f32x4 x0 = *(const f32x4*)src;
    f32x4 x1 = *(const f32x4*)(src + 4);
    *(s16x8*)dst = pack8(x0, x1);
}

// One block per batch row b: softmax over L=196 scores; att_res = sum_l p_l*att[b,l,:]
// (f32x4 loads, block halves cover even/odd l, LDS cross-half reduce);
// X[b] = [xt | att_res | h_prev] packed bf16 (K=1536) for the gates GEMM.
__global__ __launch_bounds__(256) void softmax_attres(
    const float* __restrict__ att, const float* __restrict__ scores,
    const float* __restrict__ xt, const float* __restrict__ h0,
    u16* __restrict__ X)
{
    const int b = blockIdx.x;
    const int tid = threadIdx.x;
    __shared__ float p[200];
    __shared__ float redm[4], reds[4];
    __shared__ float accu[128 * 4];

    float s = (tid < 196) ? scores[b * 196 + tid] : -3.0e38f;
    float m = s;
    #pragma unroll
    for (int d = 32; d; d >>= 1) m = fmaxf(m, __shfl_xor(m, d));
    if ((tid & 63) == 0) redm[tid >> 6] = m;
    __syncthreads();
    m = fmaxf(fmaxf(redm[0], redm[1]), fmaxf(redm[2], redm[3]));

    float e = (tid < 196) ? __expf(s - m) : 0.f;
    float sum = e;
    #pragma unroll
    for (int d = 32; d; d >>= 1) sum += __shfl_xor(sum, d);
    if ((tid & 63) == 0) reds[tid >> 6] = sum;
    __syncthreads();
    sum = reds[0] + reds[1] + reds[2] + reds[3];
    if (tid < 196) p[tid] = e / sum;
    __syncthreads();

    const float* attb = att + (size_t)b * 196 * 512;
    const int half = tid >> 7;           // waves 0,1 -> even l; waves 2,3 -> odd l
    const int e4   = (tid & 127) * 4;    // feature base 0..508
    f32x4 a = {0.f, 0.f, 0.f, 0.f};
    for (int lq = half; lq < 196; lq += 2) {
        f32x4 u = *(const f32x4*)(attb + (size_t)lq * 512 + e4);
        float pl = p[lq];
        a[0] = fmaf(pl, u[0], a[0]);
        a[1] = fmaf(pl, u[1], a[1]);
        a[2] = fmaf(pl, u[2], a[2]);
        a[3] = fmaf(pl, u[3], a[3]);
    }
    if (half) *(f32x4*)(accu + (tid & 127) * 4) = a;
    __syncthreads();

    u16* Xr = X + (size_t)b * 1536;
    if (!half) {
        f32x4 o = *(const f32x4*)(accu + tid * 4);
        a[0] += o[0]; a[1] += o[1]; a[2] += o[2]; a[3] += o[3];
        ((u32*)(Xr + 512 + e4))[0] = ((u32)f2bf(a[1]) << 16) | (u32)f2bf(a[0]);
        ((u32*)(Xr + 512 + e4))[1] = ((u32)f2bf(a[3]) << 16) | (u32)f2bf(a[2]);
    }
    f32x2 xv = ((const f32x2*)(xt + (size_t)b * 512))[tid];
    ((u32*)Xr)[tid] = ((u32)f2bf(xv[1]) << 16) | (u32)f2bf(xv[0]);
    f32x2 hv = ((const f32x2*)(h0 + (size_t)b * 512))[tid];
    ((u32*)(Xr + 1024))[tid] = ((u32)f2bf(hv[1]) << 16) | (u32)f2bf(hv[0]);
}

// Elementwise LSTM: gate order i,f,g,o. out = [h | h | c] fp32.
__global__ __launch_bounds__(256) void lstm_ep(
    const float* __restrict__ gates, const float* __restrict__ c0, float* __restrict__ out)
{
    int idx = blockIdx.x * 256 + threadIdx.x;     // 0..262143
    int b = idx >> 9, hh = idx & 511;
    const float* g = gates + ((size_t)b << 11);
    float i_ = sigm(g[hh]);
    float f_ = sigm(g[512 + hh]);
    float g_ = tanh_fast(g[1024 + hh]);
    float o_ = sigm(g[1536 + hh]);
    float c = f_ * c0[idx] + i_ * g_;
    float h = o_ * tanh_fast(c);
    out[idx] = h;
    out[262144 + idx] = h;
    out[524288 + idx] = c;
}

extern "C" void kernel_launch(void* const* d_in, const int* in_sizes, int n_in,
                              void* d_out, int out_size, void* d_ws, size_t ws_size,
                              hipStream_t stream) {
    const float* xt   = (const float*)d_in[0];
    // d_in[1] = fc_feats (unused by reference)
    const float* att  = (const float*)d_in[2];
    const float* h0   = (const float*)d_in[3];
    const float* c0   = (const float*)d_in[4];
    const float* Wctx = (const float*)d_in[5];
    const float* bctx = (const float*)d_in[6];
    const float* Whid = (const float*)d_in[7];
    const float* bhid = (const float*)d_in[8];
    const float* wsc  = (const float*)d_in[9];
    // d_in[10] = b_score (cancels under softmax)
    const float* Wih  = (const float*)d_in[11];
    const float* Whh  = (const float*)d_in[12];
    float* out = (float*)d_out;

    char* ws = (char*)d_ws;
    float* hidb   = (float*)(ws);                 // 512*512 f32    @ 0
    float* scores = (float*)(ws + 1048576);       // 100352 f32
    float* gates  = (float*)(ws + 1449984);       // 512*2048 f32
    u16*   Xb     = (u16*)  (ws + 5644288);       // 512*1536 bf16
    u16*   Wctxb  = (u16*)  (ws + 7217152);       // 512*512 bf16
    u16*   Whidb  = (u16*)  (ws + 7741440);       // 512*512 bf16
    u16*   Wgb    = (u16*)  (ws + 8265728);       // 2048*1536 bf16 (ends 14557184)

    // zero the atomically-accumulated regions (hidb + scores + gates)
    hipMemsetAsync(ws, 0, 5644288, stream);

    // 0) weights -> bf16 (Wctxb, Whidb, Wgb=[Wih|Whh])
    cvt_w<<<1792, 256, 0, stream>>>(Wctx, Whid, Wih, Whh, Wctxb, Whidb, Wgb);

    // 1) hidb[b,a] += h_prev @ W_hid^T   (A=f32 h0, B=bf16; split-K=4)
    gemm<2, true><<<dim3(4, 4, 4), 256, 0, stream>>>(
        h0, Whidb, 512, 512, 512, 128,
        hidb, nullptr, nullptr, nullptr, nullptr, nullptr);

    // 2) scores[b,l] += sum_a tanh(att@Wctx^T + hidb + b_hid + b_ctx)*w_score
    gemm<1, true><<<dim3(4, 784, 1), 256, 0, stream>>>(
        att, Wctxb, 512, 512, 512, 512,
        nullptr, bhid, bctx, hidb, wsc, scores);

    // 3) softmax + att_res + X = [xt | att_res | h_prev] (bf16)
    softmax_attres<<<512, 256, 0, stream>>>(att, scores, xt, h0, Xb);

    // 4) gates = X @ [W_ih | W_hh]^T   (A=bf16 X, M=512,N=2048,K=1536, split-K=4)
    gemm<2, false><<<dim3(16, 4, 4), 256, 0, stream>>>(
        Xb, Wgb, 1536, 1536, 2048, 384,
        gates, nullptr, nullptr, nullptr, nullptr, nullptr);

    // 5) elementwise LSTM -> out = [h | h | c] fp32
    lstm_ep<<<1024, 256, 0, stream>>>(gates, c0, out);
}

// Round 14
// 459.544 us; speedup vs baseline: 1.1520x; 1.0849x over previous
//
#include <hip/hip_runtime.h>
#include <stdint.h>

typedef unsigned short u16;
typedef unsigned int   u32;
typedef __attribute__((ext_vector_type(2))) float f32x2;
typedef __attribute__((ext_vector_type(4))) float f32x4;
typedef __attribute__((ext_vector_type(8))) short s16x8;

typedef const __attribute__((address_space(1))) void as1_void;
typedef __attribute__((address_space(3))) void as3_void;

__device__ __forceinline__ u16 f2bf(float f) {
    u32 x = __float_as_uint(f);
    x += 0x7fffu + ((x >> 16) & 1u);
    return (u16)(x >> 16);
}
__device__ __forceinline__ float tanh_fast(float x) {
    return 1.f - 2.f / (__expf(2.f * x) + 1.f);
}
__device__ __forceinline__ float sigm(float x) {
    return 1.f / (1.f + __expf(-x));
}
// pack 8 f32 (two f32x4) -> 8 bf16 by truncation (v_perm byte-selects)
__device__ __forceinline__ s16x8 pack8(f32x4 x0, f32x4 x1) {
    union { s16x8 v; u32 w[4]; } r;
    r.w[0] = __builtin_amdgcn_perm(__float_as_uint(x0[1]), __float_as_uint(x0[0]), 0x07060302u);
    r.w[1] = __builtin_amdgcn_perm(__float_as_uint(x0[3]), __float_as_uint(x0[2]), 0x07060302u);
    r.w[2] = __builtin_amdgcn_perm(__float_as_uint(x1[1]), __float_as_uint(x1[0]), 0x07060302u);
    r.w[3] = __builtin_amdgcn_perm(__float_as_uint(x1[3]), __float_as_uint(x1[2]), 0x07060302u);
    return r.v;
}

#define BM 128
#define BN 128
#define BK 64

// r13 structure + bank-conflict swizzle (single changed variable).
// LDS dest linear (gload_lds HW requirement); global SOURCE 16B-chunk index
// XOR-permuted by (row&7); all fragment reads apply the same XOR.
// Read bank-quad = (chunk^(row&7))&7 -> uniform 8 lanes/quad per b128 (minimum).
template<int EPI, bool AF32>
__global__ __launch_bounds__(256) void gemm(
    const void* __restrict__ Ag, const u16* __restrict__ Bg,
    int lda, int ldb, int N, int klen,
    float* __restrict__ outF,
    const float* __restrict__ bias1, const float* __restrict__ bias2,
    const float* __restrict__ hidb, const float* __restrict__ wscore,
    float* __restrict__ scores)
{
    constexpr int ABYTES = AF32 ? (BM * BK * 4) : (BM * BK * 2);
    __shared__ __align__(16) char Abuf[ABYTES];
    __shared__ __align__(16) u16 Bsb[BN * BK];
    const int tid = threadIdx.x;
    const int l   = tid & 63;
    const int w   = tid >> 6;

    // XCD-aware bijective remap (nwg % 8 == 0 for all our grids)
    const int nbx = gridDim.x;
    const int nwg = nbx * gridDim.y;
    const int p   = blockIdx.x + blockIdx.y * nbx;
    const int per = nwg >> 3;
    const int lg  = (p & 7) * per + (p >> 3);
    const int n0  = (lg % nbx) * BN;
    const int m0  = (lg / nbx) * BM;

    const int kbeg   = blockIdx.z * klen;
    const int nsteps = klen / BK;
    const int wr = (w >> 1) * 64;
    const int wc = (w & 1) * 64;

    auto STAGE = [&](int kt) {
        if constexpr (AF32) {
            #pragma unroll
            for (int c = 0; c < 8; ++c) {            // A: 32 KB, 16 chunks/row
                const int slot = c * 256 + tid;
                const int row = slot >> 4;
                const int sch = (slot & 15) ^ (row & 7);   // swizzled source chunk
                const float* ga = (const float*)Ag + (size_t)(m0 + row) * lda + kt + sch * 4;
                __builtin_amdgcn_global_load_lds((as1_void*)ga,
                    (as3_void*)(Abuf + (c * 256 + w * 64) * 16), 16, 0, 0);
            }
        } else {
            #pragma unroll
            for (int c = 0; c < 4; ++c) {            // A: 16 KB, 8 chunks/row
                const int slot = c * 256 + tid;
                const int row = slot >> 3;
                const int sch = (slot & 7) ^ (row & 7);
                const u16* ga = (const u16*)Ag + (size_t)(m0 + row) * lda + kt + sch * 8;
                __builtin_amdgcn_global_load_lds((as1_void*)ga,
                    (as3_void*)(Abuf + (c * 256 + w * 64) * 16), 16, 0, 0);
            }
        }
        #pragma unroll
        for (int c = 0; c < 4; ++c) {                // B: 16 KB, 8 chunks/row
            const int slot = c * 256 + tid;
            const int row = slot >> 3;
            const int sch = (slot & 7) ^ (row & 7);
            const u16* gb = Bg + (size_t)(n0 + row) * ldb + kt + sch * 8;
            __builtin_amdgcn_global_load_lds((as1_void*)gb,
                (as3_void*)((char*)Bsb + (c * 256 + w * 64) * 16), 16, 0, 0);
        }
    };

    f32x4 acc[4][4] = {};

    for (int s = 0; s < nsteps; ++s) {
        STAGE(kbeg + s * BK);
        __syncthreads();     // vmcnt(0) drain; tile visible
        #pragma unroll
        for (int kk = 0; kk < BK; kk += 32) {
            s16x8 af[4], bg[4];
            #pragma unroll
            for (int i = 0; i < 4; ++i) {
                const int row = wr + i * 16 + (l & 15);
                if constexpr (AF32) {
                    // global chunk pair (cb, cb+1); LDS chunk = g ^ (row&7)
                    const int cb = (kk >> 2) + (l >> 4) * 2;
                    const float* base = (const float*)Abuf + row * BK;
                    f32x4 x0 = *(const f32x4*)(base + ((cb ^ (row & 7)) * 4));
                    f32x4 x1 = *(const f32x4*)(base + (((cb + 1) ^ (row & 7)) * 4));
                    af[i] = pack8(x0, x1);
                } else {
                    const int g = (kk >> 3) + (l >> 4);
                    af[i] = *(const s16x8*)((const u16*)Abuf + row * BK + ((g ^ (row & 7)) * 8));
                }
            }
            #pragma unroll
            for (int j = 0; j < 4; ++j) {
                const int row = wc + j * 16 + (l & 15);
                const int g = (kk >> 3) + (l >> 4);
                bg[j] = *(const s16x8*)(Bsb + row * BK + ((g ^ (row & 7)) * 8));
            }
            #pragma unroll
            for (int i = 0; i < 4; ++i)
                #pragma unroll
                for (int j = 0; j < 4; ++j)
                    acc[i][j] = __builtin_amdgcn_mfma_f32_16x16x32_bf16(af[i], bg[j], acc[i][j], 0, 0, 0);
        }
        __syncthreads();     // all reads done before next overwrite
    }

    // C/D layout (m89-verified): col = lane&15, row = (lane>>4)*4 + reg
    const int col0 = l & 15;
    const int rgrp = l >> 4;

    if (EPI == 1) {
        float wsv[4], bs[4]; int gcol[4];
        #pragma unroll
        for (int j = 0; j < 4; ++j) {
            gcol[j] = n0 + wc + j * 16 + col0;
            wsv[j] = wscore[gcol[j]];
            bs[j]  = bias1[gcol[j]] + bias2[gcol[j]];
        }
        #pragma unroll
        for (int i = 0; i < 4; ++i) {
            #pragma unroll
            for (int q = 0; q < 4; ++q) {
                int grow = m0 + wr + i * 16 + rgrp * 4 + q;
                int bb = grow / 196;
                const float* hb = hidb + (size_t)bb * N;
                float s = 0.f;
                #pragma unroll
                for (int j = 0; j < 4; ++j) {
                    float x = acc[i][j][q] + hb[gcol[j]] + bs[j];
                    s += tanh_fast(x) * wsv[j];
                }
                s += __shfl_xor(s, 1);
                s += __shfl_xor(s, 2);
                s += __shfl_xor(s, 4);
                s += __shfl_xor(s, 8);
                if (col0 == 0) atomicAdd(&scores[grow], s);
            }
        }
    } else {
        #pragma unroll
        for (int j = 0; j < 4; ++j) {
            int gcol = n0 + wc + j * 16 + col0;
            #pragma unroll
            for (int i = 0; i < 4; ++i)
                #pragma unroll
                for (int q = 0; q < 4; ++q) {
                    int grow = m0 + wr + i * 16 + rgrp * 4 + q;
                    atomicAdd(&outF[(size_t)grow * N + gcol], acc[i][j][q]);
                }
        }
    }
}

// Convert weights f32 -> bf16 (truncation), incl. [W_ih | W_hh] k-concat into Wg.
__global__ __launch_bounds__(256) void cvt_w(
    const float* __restrict__ Wctx, const float* __restrict__ Whid,
    const float* __restrict__ Wih,  const float* __restrict__ Whh,
    u16* __restrict__ Wctxb, u16* __restrict__ Whidb, u16* __restrict__ Wgb)
{
    const int gid = blockIdx.x * 256 + threadIdx.x;   // 458752 total groups of 8
    const float* src;
    u16* dst;
    if (gid < 32768) {
        src = Wctx + (size_t)gid * 8;
        dst = Wctxb + (size_t)gid * 8;
    } else if (gid < 65536) {
        src = Whid + (size_t)(gid - 32768) * 8;
        dst = Whidb + (size_t)(gid - 32768) * 8;
    } else {
        const int g2 = gid - 65536;          // 0..393215
        const int n  = g2 / 192;             // 192 groups of 8 per 1536-row
        const int k8 = (g2 - n * 192) * 8;   // 0..1528
        dst = Wgb + (size_t)n * 1536 + k8;
        src = (k8 < 1024) ? (Wih + (size_t)n * 1024 + k8)
                          : (Whh + (size_t)n * 512 + (k8 - 1024));
    }
    f32x4 x0 = *(const f32x4*)src;
    f32x4 x1 = *(const f32x4*)(src + 4);
    *(s16x8*)dst = pack8(x0, x1);
}

// One block per batch row b: softmax over L=196 scores; att_res = sum_l p_l*att[b,l,:]
// X[b] = [xt | att_res | h_prev] packed bf16 (K=1536) for the gates GEMM.
__global__ __launch_bounds__(256) void softmax_attres(
    const float* __restrict__ att, const float* __restrict__ scores,
    const float* __restrict__ xt, const float* __restrict__ h0,
    u16* __restrict__ X)
{
    const int b = blockIdx.x;
    const int tid = threadIdx.x;
    __shared__ float p[200];
    __shared__ float redm[4], reds[4];
    __shared__ float accu[128 * 4];

    float s = (tid < 196) ? scores[b * 196 + tid] : -3.0e38f;
    float m = s;
    #pragma unroll
    for (int d = 32; d; d >>= 1) m = fmaxf(m, __shfl_xor(m, d));
    if ((tid & 63) == 0) redm[tid >> 6] = m;
    __syncthreads();
    m = fmaxf(fmaxf(redm[0], redm[1]), fmaxf(redm[2], redm[3]));

    float e = (tid < 196) ? __expf(s - m) : 0.f;
    float sum = e;
    #pragma unroll
    for (int d = 32; d; d >>= 1) sum += __shfl_xor(sum, d);
    if ((tid & 63) == 0) reds[tid >> 6] = sum;
    __syncthreads();
    sum = reds[0] + reds[1] + reds[2] + reds[3];
    if (tid < 196) p[tid] = e / sum;
    __syncthreads();

    const float* attb = att + (size_t)b * 196 * 512;
    const int half = tid >> 7;           // waves 0,1 -> even l; waves 2,3 -> odd l
    const int e4   = (tid & 127) * 4;    // feature base 0..508
    f32x4 a = {0.f, 0.f, 0.f, 0.f};
    for (int lq = half; lq < 196; lq += 2) {
        f32x4 u = *(const f32x4*)(attb + (size_t)lq * 512 + e4);
        float pl = p[lq];
        a[0] = fmaf(pl, u[0], a[0]);
        a[1] = fmaf(pl, u[1], a[1]);
        a[2] = fmaf(pl, u[2], a[2]);
        a[3] = fmaf(pl, u[3], a[3]);
    }
    if (half) *(f32x4*)(accu + (tid & 127) * 4) = a;
    __syncthreads();

    u16* Xr = X + (size_t)b * 1536;
    if (!half) {
        f32x4 o = *(const f32x4*)(accu + tid * 4);
        a[0] += o[0]; a[1] += o[1]; a[2] += o[2]; a[3] += o[3];
        ((u32*)(Xr + 512 + e4))[0] = ((u32)f2bf(a[1]) << 16) | (u32)f2bf(a[0]);
        ((u32*)(Xr + 512 + e4))[1] = ((u32)f2bf(a[3]) << 16) | (u32)f2bf(a[2]);
    }
    f32x2 xv = ((const f32x2*)(xt + (size_t)b * 512))[tid];
    ((u32*)Xr)[tid] = ((u32)f2bf(xv[1]) << 16) | (u32)f2bf(xv[0]);
    f32x2 hv = ((const f32x2*)(h0 + (size_t)b * 512))[tid];
    ((u32*)(Xr + 1024))[tid] = ((u32)f2bf(hv[1]) << 16) | (u32)f2bf(hv[0]);
}

// Elementwise LSTM: gate order i,f,g,o. out = [h | h | c] fp32.
__global__ __launch_bounds__(256) void lstm_ep(
    const float* __restrict__ gates, const float* __restrict__ c0, float* __restrict__ out)
{
    int idx = blockIdx.x * 256 + threadIdx.x;     // 0..262143
    int b = idx >> 9, hh = idx & 511;
    const float* g = gates + ((size_t)b << 11);
    float i_ = sigm(g[hh]);
    float f_ = sigm(g[512 + hh]);
    float g_ = tanh_fast(g[1024 + hh]);
    float o_ = sigm(g[1536 + hh]);
    float c = f_ * c0[idx] + i_ * g_;
    float h = o_ * tanh_fast(c);
    out[idx] = h;
    out[262144 + idx] = h;
    out[524288 + idx] = c;
}

extern "C" void kernel_launch(void* const* d_in, const int* in_sizes, int n_in,
                              void* d_out, int out_size, void* d_ws, size_t ws_size,
                              hipStream_t stream) {
    const float* xt   = (const float*)d_in[0];
    // d_in[1] = fc_feats (unused by reference)
    const float* att  = (const float*)d_in[2];
    const float* h0   = (const float*)d_in[3];
    const float* c0   = (const float*)d_in[4];
    const float* Wctx = (const float*)d_in[5];
    const float* bctx = (const float*)d_in[6];
    const float* Whid = (const float*)d_in[7];
    const float* bhid = (const float*)d_in[8];
    const float* wsc  = (const float*)d_in[9];
    // d_in[10] = b_score (cancels under softmax)
    const float* Wih  = (const float*)d_in[11];
    const float* Whh  = (const float*)d_in[12];
    float* out = (float*)d_out;

    char* ws = (char*)d_ws;
    float* hidb   = (float*)(ws);                 // 512*512 f32    @ 0
    float* scores = (float*)(ws + 1048576);       // 100352 f32
    float* gates  = (float*)(ws + 1449984);       // 512*2048 f32
    u16*   Xb     = (u16*)  (ws + 5644288);       // 512*1536 bf16
    u16*   Wctxb  = (u16*)  (ws + 7217152);       // 512*512 bf16
    u16*   Whidb  = (u16*)  (ws + 7741440);       // 512*512 bf16
    u16*   Wgb    = (u16*)  (ws + 8265728);       // 2048*1536 bf16 (ends 14557184)

    // zero the atomically-accumulated regions (hidb + scores + gates)
    hipMemsetAsync(ws, 0, 5644288, stream);

    // 0) weights -> bf16 (Wctxb, Whidb, Wgb=[Wih|Whh])
    cvt_w<<<1792, 256, 0, stream>>>(Wctx, Whid, Wih, Whh, Wctxb, Whidb, Wgb);

    // 1) hidb[b,a] += h_prev @ W_hid^T   (A=f32 h0, B=bf16; split-K=4)
    gemm<2, true><<<dim3(4, 4, 4), 256, 0, stream>>>(
        h0, Whidb, 512, 512, 512, 128,
        hidb, nullptr, nullptr, nullptr, nullptr, nullptr);

    // 2) scores[b,l] += sum_a tanh(att@Wctx^T + hidb + b_hid + b_ctx)*w_score
    gemm<1, true><<<dim3(4, 784, 1), 256, 0, stream>>>(
        att, Wctxb, 512, 512, 512, 512,
        nullptr, bhid, bctx, hidb, wsc, scores);

    // 3) softmax + att_res + X = [xt | att_res | h_prev] (bf16)
    softmax_attres<<<512, 256, 0, stream>>>(att, scores, xt, h0, Xb);

    // 4) gates = X @ [W_ih | W_hh]^T   (A=bf16 X, M=512,N=2048,K=1536, split-K=4)
    gemm<2, false><<<dim3(16, 4, 4), 256, 0, stream>>>(
        Xb, Wgb, 1536, 1536, 2048, 384,
        gates, nullptr, nullptr, nullptr, nullptr, nullptr);

    // 5) elementwise LSTM -> out = [h | h | c] fp32
    lstm_ep<<<1024, 256, 0, stream>>>(gates, c0, out);
}